// Round 12
// baseline (4896.006 us; speedup 1.0000x reference)
//
#include <hip/hip_runtime.h>

// ---------------- problem constants ----------------
#define Tn   2048
#define Bn   64
#define INn  27
#define H1n  400
#define KP   416          // padded fc K — Wfc row stride
#define NSL  50           // producer blocks (slices), 8 units each
#define NHB  13           // head blocks (fc tiles of 16 rows)
#define RING 8            // h ring depth; epoch parity = (t>>3)&1
// hbuf: [slot][g][s:52][r:16][u:8] bf16; 256 B per (g,s), wave-exclusive
#define HB_G    13312u    // 52 slice blocks (50 real + 2 pad) * 256 B
#define HB_SLOT 53248u    // 4 groups * HB_G

using short8 = __attribute__((ext_vector_type(8))) short;   // 8 bf16
using f32x4  = __attribute__((ext_vector_type(4))) float;   // MFMA acc
using uint4v = __attribute__((ext_vector_type(4))) unsigned;

// ---------------- workspace layout (bytes) ----------------
#define OFF_WBIG  0u         // bf16 [1600][448]  [Whh|pad|Wih]       1,433,600
#define OFF_WFC   1433600u   // bf16 [208][416]                         173,056
#define OFF_BSUM  1606656u   // f32  [1600]                               6,400
#define OFF_BFC   1613056u   // f32  [208]                                  832
#define OFF_WOUT  1613888u   // f32  [208]                                  832
#define OFF_HBUF  1614720u   // bf16 ring [8][4][52][16][8]             425,984
#define OFF_PROG  2040704u   // u32  [4][64] head progress                1,024
#define OFF_YPART 2041728u   // f32  [13][2048*64] head partials      6,815,744
// total 8,857,472

__device__ __forceinline__ unsigned short f2bf(float f) {
  unsigned u = __builtin_bit_cast(unsigned, f);
  u += 0x7fffu + ((u >> 16) & 1u);          // round-to-nearest-even
  return (unsigned short)(u >> 16);
}
__device__ __forceinline__ float sigm(float x) {
  float e = __builtin_amdgcn_exp2f(-1.44269504f * x);
  return __builtin_amdgcn_rcpf(1.0f + e);
}
__device__ __forceinline__ float tanh_(float x) {
  float e = __builtin_amdgcn_exp2f(2.88539008f * x);
  return 1.0f - 2.0f * __builtin_amdgcn_rcpf(e + 1.0f);
}

// ---- agent-coherent (sc0 sc1: L1/L2 bypass, L3 coherence point) ops ----
__device__ __forceinline__ unsigned ld_u32_wait(const unsigned* p) {
  unsigned v;
  asm volatile("global_load_dword %0, %1, off sc0 sc1\n\ts_waitcnt vmcnt(0)"
               : "=v"(v) : "v"(p) : "memory");
  return v;
}
__device__ __forceinline__ unsigned ld_u32_nw(const unsigned* p) {
  unsigned v;
  asm volatile("global_load_dword %0, %1, off sc0 sc1" : "=v"(v) : "v"(p) : "memory");
  return v;
}
__device__ __forceinline__ short8 ld_h16(const void* p) {
  short8 v;
  asm volatile("global_load_dwordx4 %0, %1, off sc0 sc1" : "=v"(v) : "v"(p) : "memory");
  return v;
}
__device__ __forceinline__ void st_h16(void* p, short8 v) {
  asm volatile("global_store_dwordx4 %0, %1, off sc0 sc1" :: "v"(p), "v"(v) : "memory");
}
__device__ __forceinline__ void st_u32(void* p, unsigned v) {
  asm volatile("global_store_dword %0, %1, off sc0 sc1" :: "v"(p), "v"(v) : "memory");
}

// MFMA with B operand pinned in AGPRs (weights resident; proven R5/R8/R9).
__device__ __forceinline__ f32x4 mfma_aw(short8 a, short8 w_agpr, f32x4 acc) {
  asm("v_mfma_f32_16x16x32_bf16 %0, %1, %2, %0"
      : "+v"(acc) : "v"(a), "a"(w_agpr));
  return acc;
}

// canary spin: cheap 16B-per-lane wait on chunk 0 (slices 0..3, all real).
// Correctness does NOT depend on it — the full verified read follows.
__device__ __forceinline__ void canary_wait(const char* hsrc, bool expm) {
  while (true) {
    short8 cv = ld_h16(hsrc);
    asm volatile("s_waitcnt vmcnt(0)" ::: "memory");
    uint4v u = __builtin_bit_cast(uint4v, cv);
    bool ok;
    if (expm) {
      unsigned d = u.x & u.y & u.z & u.w;
      ok = ((d & 0x80008000u) == 0x80008000u);
    } else {
      unsigned d = u.x | u.y | u.z | u.w;
      ok = ((d & 0x80008000u) == 0u);
    }
    if (__all((int)ok)) break;
  }
}

// rowp (0..1599) -> original gate row. Slice s owns units 8s..8s+7 as
// 2 tiles: tile0 = gates i|f, tile1 = g|o (i/f split at col bit 3).
__device__ __forceinline__ int gate_row(int rowp) {
  int s    = rowp >> 5;
  int r32  = rowp & 31;
  int tile = r32 >> 4;
  int c    = r32 & 15;
  int gate = tile * 2 + (c >> 3);
  int u    = s * 8 + (c & 7);
  return gate * H1n + u;
}

// ---------------- prep ----------------
__global__ void prep_kernel(const float* __restrict__ Wih, const float* __restrict__ Whh,
                            const float* __restrict__ bih, const float* __restrict__ bhh,
                            const float* __restrict__ Wfc, const float* __restrict__ bfc,
                            const float* __restrict__ Wout,
                            unsigned char* __restrict__ ws)
{
  size_t i = (size_t)blockIdx.x * blockDim.x + threadIdx.x;
  const size_t n1 = (size_t)1600 * 448;   // Wbig       716800
  const size_t n2 = (size_t)208 * KP;     // Wfc          86528
  const size_t n3 = 1600;                 // bsum
  const size_t n4 = 208;                  // bfc
  const size_t n5 = 208;                  // wout
  const size_t n6 = (size_t)RING * HB_SLOT / 2;  // hbuf shorts 212992
  const size_t n7 = 256;                  // progress words

  if (i < n1) {
    unsigned short* p = (unsigned short*)(ws + OFF_WBIG);
    int rowp = (int)(i / 448), k = (int)(i % 448);
    int r = gate_row(rowp);
    float v = 0.0f;
    if (k < H1n)            v = Whh[(size_t)r * H1n + k];
    else if (k >= 416) { int jj = k - 416; if (jj < INn) v = Wih[(size_t)r * INn + jj]; }
    p[i] = f2bf(v);
    return;
  }
  i -= n1;
  if (i < n2) {
    unsigned short* p = (unsigned short*)(ws + OFF_WFC);
    int r = (int)(i / KP), k = (int)(i % KP);
    p[i] = (r < 200 && k < H1n) ? f2bf(Wfc[(size_t)r * H1n + k]) : (unsigned short)0;
    return;
  }
  i -= n2;
  if (i < n3) { int r = gate_row((int)i);
    ((float*)(ws + OFF_BSUM))[i] = bih[r] + bhh[r]; return; }
  i -= n3;
  if (i < n4) { ((float*)(ws + OFF_BFC))[i] = (i < 200) ? bfc[i] : 0.0f; return; }
  i -= n4;
  if (i < n5) { ((float*)(ws + OFF_WOUT))[i] = (i < 200) ? Wout[i] : 0.0f; return; }
  i -= n5;
  // hbuf init: 0x8000 (= parity 1) so epoch-0 (parity 0) checks can't
  // false-positive on unwritten data.
  if (i < n6) { ((unsigned short*)(ws + OFF_HBUF))[i] = 0x8000u; return; }
  i -= n6;
  if (i < n7) { ((unsigned*)(ws + OFF_PROG))[i] = 0u; return; }
}

// ---------------- persistent LSTM ----------------
// EXACT R9 structure (passed correctness + determinism tripwire), plus a
// canary spin before each full verified read. 63 blocks x 256 thr (wave =
// batch group). Blocks 0..49: producers (8 units, 2 gate tiles, AGPR
// weights). Blocks 50..62: heads (fc tile p). SYNC: parity-in-sign-bit
// (h_r >= 0); consumers accept only a fully parity-verified 13-chunk read.
// Heads report consumed-step in prog[]; producers gate publish on head
// progress >= t-7 (ring-overwrite safety).
__global__ void __launch_bounds__(256, 1)
lstm_persist(const float* __restrict__ word, unsigned char* __restrict__ ws)
{
  const int l  = threadIdx.x & 63;
  const int g  = threadIdx.x >> 6;   // batch group 0..3
  const int lg = l >> 4, ln = l & 15;
  const int b0 = g * 16;

  const unsigned short* Wbig = (const unsigned short*)(ws + OFF_WBIG);
  const unsigned short* Wfc2 = (const unsigned short*)(ws + OFF_WFC);
  const float* bsum  = (const float*)(ws + OFF_BSUM);
  const float* bfc2  = (const float*)(ws + OFF_BFC);
  const float* wout2 = (const float*)(ws + OFF_WOUT);
  char* hbase = (char*)(ws + OFF_HBUF);
  unsigned* prog = (unsigned*)(ws + OFF_PROG);
  float* yPart = (float*)(ws + OFF_YPART);

  // consumer fragment address: chunk kc covers slices kc*4+lg
  const size_t hoff = (size_t)g * HB_G + (size_t)lg * 256 + (size_t)ln * 16;

  __shared__ __align__(16) unsigned short smt2[4][16][8];   // [g][row][unit]

  if (blockIdx.x < NSL) {
    // ================= producer path =================
    const int s = blockIdx.x;

    short8 wv0[13], wv1[13], wx0, wx1;
#pragma unroll
    for (int kc = 0; kc < 13; ++kc) {
      wv0[kc] = *(const short8*)(Wbig + (size_t)(s * 32 + ln)      * 448 + kc * 32 + lg * 8);
      wv1[kc] = *(const short8*)(Wbig + (size_t)(s * 32 + 16 + ln) * 448 + kc * 32 + lg * 8);
    }
    wx0 = *(const short8*)(Wbig + (size_t)(s * 32 + ln)      * 448 + 13 * 32 + lg * 8);
    wx1 = *(const short8*)(Wbig + (size_t)(s * 32 + 16 + ln) * 448 + 13 * 32 + lg * 8);
    const float bs0 = bsum[s * 32 + ln];
    const float bs1 = bsum[s * 32 + 16 + ln];

    float c[4] = {0.f, 0.f, 0.f, 0.f};
    short8 ha[13];

    short8 xa;
    {
      const float* xrow = word + ((size_t)0 * Bn + b0 + ln) * INn;
#pragma unroll
      for (int q = 0; q < 8; ++q) {
        const int k = lg * 8 + q;
        xa[q] = (short)f2bf((k < INn) ? xrow[k] : 0.0f);
      }
    }

    for (int t = 0; t < Tn; ++t) {
      // ---- head-progress early load (monotonic -> stale-safe) ----
      unsigned hp = 0xFFFFFFFFu;
      if (l < NHB) hp = ld_u32_nw(&prog[g * 64 + l]);

      // ---- poll h(t-1) by parity: canary spin, then full verified read ----
      if (t > 0) {
        const char* hsrc = hbase + (size_t)((t + RING - 1) & (RING - 1)) * HB_SLOT + hoff;
        const bool expm = (((t - 1) >> 3) & 1) != 0;
        canary_wait(hsrc, expm);
        while (true) {
#pragma unroll
          for (int kc = 0; kc < 13; ++kc)
            ha[kc] = ld_h16(hsrc + kc * 1024);
          asm volatile("s_waitcnt vmcnt(0)" ::: "memory");
          __builtin_amdgcn_sched_barrier(0);
          bool ok;
          if (expm) {
            unsigned r = 0xFFFFFFFFu;
#pragma unroll
            for (int kc = 0; kc < 13; ++kc) {
              uint4v u = __builtin_bit_cast(uint4v, ha[kc]);
              unsigned d = u.x & u.y & u.z & u.w;
              if (kc == 12) d = (lg < 2) ? d : 0xFFFFFFFFu;   // mask pad slices
              r &= d;
            }
            ok = ((r & 0x80008000u) == 0x80008000u);
          } else {
            unsigned r = 0u;
#pragma unroll
            for (int kc = 0; kc < 13; ++kc) {
              uint4v u = __builtin_bit_cast(uint4v, ha[kc]);
              unsigned d = u.x | u.y | u.z | u.w;
              if (kc == 12) d = (lg < 2) ? d : 0u;             // mask pad slices
              r |= d;
            }
            ok = ((r & 0x80008000u) == 0u);
          }
          if (__all((int)ok)) break;
        }
        if (expm) {
#pragma unroll
          for (int kc = 0; kc < 13; ++kc) {
            uint4v u = __builtin_bit_cast(uint4v, ha[kc]);
            u.x &= 0x7FFF7FFFu; u.y &= 0x7FFF7FFFu;
            u.z &= 0x7FFF7FFFu; u.w &= 0x7FFF7FFFu;
            ha[kc] = __builtin_bit_cast(short8, u);
          }
        }
        if (lg >= 2) {          // pad-slice garbage: zero (NaN x 0 = NaN!)
          short8 z;
#pragma unroll
          for (int q = 0; q < 8; ++q) z[q] = 0;
          ha[12] = z;
        }
      }

      // ---- gates: 2 tiles x (13 h + 1 x) MFMA, weights from AGPRs ----
      f32x4 a0 = {bs0, bs0, bs0, bs0};
      f32x4 a1 = {bs1, bs1, bs1, bs1};
      if (t > 0) {
#pragma unroll
        for (int kc = 0; kc < 13; ++kc) {
          a0 = mfma_aw(ha[kc], wv0[kc], a0);
          a1 = mfma_aw(ha[kc], wv1[kc], a1);
        }
      }
      a0 = mfma_aw(xa, wx0, a0);
      a1 = mfma_aw(xa, wx1, a1);

      // ---- cell update; lanes l and l^8 share unit, hold i/f and g/o ----
      const bool hiHalf = (l & 8) != 0;
      float hr[4];
#pragma unroll
      for (int v = 0; v < 4; ++v) {
        float o0 = a0[v], o1 = a1[v];
        float p0 = __shfl_xor(o0, 8);
        float p1 = __shfl_xor(o1, 8);
        float iv = hiHalf ? p0 : o0;
        float fv = hiHalf ? o0 : p0;
        float gv = hiHalf ? p1 : o1;
        float ov = hiHalf ? o1 : p1;
        iv = sigm(iv); fv = sigm(fv); gv = tanh_(gv); ov = sigm(ov);
        float cn = fv * c[v] + iv * gv;
        float hn = ov * tanh_(cn);
        c[v]  = fmaxf(cn, 0.f);
        hr[v] = fmaxf(hn, 0.f);
      }
      // ---- wave-local transpose; embed parity of CURRENT step t ----
      const unsigned short pb = (unsigned short)(((t >> 3) & 1) << 15);
      if (!hiHalf) {
#pragma unroll
        for (int v = 0; v < 4; ++v)
          smt2[g][lg * 4 + v][ln] = (unsigned short)(f2bf(hr[v]) | pb);
      }
      asm volatile("s_waitcnt lgkmcnt(0)" ::: "memory");

      // ---- ring-overwrite gate: heads must have consumed step t-7 ----
      if (t >= RING) {
        const unsigned need = (unsigned)(t - (RING - 1));
        bool hok = (l < NHB) ? (hp >= need) : true;
        while (!__all((int)hok)) {
          if (l < NHB) hp = ld_u32_wait(&prog[g * 64 + l]);
          hok = (l < NHB) ? (hp >= need) : true;
        }
      }

      // ---- publish h(t): one exclusive 256-B block, fire-and-forget ----
      {
        char* hdst = hbase + (size_t)(t & (RING - 1)) * HB_SLOT
                   + (size_t)g * HB_G + (size_t)s * 256;
        if (l < 16) {
          short8 hv = *(const short8*)(&smt2[g][l][0]);
          st_h16(hdst + l * 16, hv);
        }
      }

      // ---- x(t+1) prefetch ----
      if (t + 1 < Tn) {
        const float* xrow = word + ((size_t)(t + 1) * Bn + b0 + ln) * INn;
#pragma unroll
        for (int q = 0; q < 8; ++q) {
          const int k = lg * 8 + q;
          xa[q] = (short)f2bf((k < INn) ? xrow[k] : 0.0f);
        }
      }
    }
  } else {
    // ================= head-consumer path =================
    const int p = blockIdx.x - NSL;      // fc tile 0..12

    short8 whv[13];
    {
      const int r = p * 16 + ln;
#pragma unroll
      for (int kc = 0; kc < 13; ++kc)
        whv[kc] = *(const short8*)(Wfc2 + (size_t)r * KP + kc * 32 + lg * 8);
    }
    const float bfcv  = bfc2[p * 16 + ln];
    const float woutv = wout2[p * 16 + ln];
    short8 ha[13];

    for (int t = 0; t < Tn; ++t) {
      // ---- poll h(t) by parity: canary spin, then full verified read ----
      const char* hsrc = hbase + (size_t)(t & (RING - 1)) * HB_SLOT + hoff;
      const bool expm = (((t >> 3) & 1) != 0);
      canary_wait(hsrc, expm);
      while (true) {
#pragma unroll
        for (int kc = 0; kc < 13; ++kc)
          ha[kc] = ld_h16(hsrc + kc * 1024);
        asm volatile("s_waitcnt vmcnt(0)" ::: "memory");
        __builtin_amdgcn_sched_barrier(0);
        bool ok;
        if (expm) {
          unsigned r = 0xFFFFFFFFu;
#pragma unroll
          for (int kc = 0; kc < 13; ++kc) {
            uint4v u = __builtin_bit_cast(uint4v, ha[kc]);
            unsigned d = u.x & u.y & u.z & u.w;
            if (kc == 12) d = (lg < 2) ? d : 0xFFFFFFFFu;
            r &= d;
          }
          ok = ((r & 0x80008000u) == 0x80008000u);
        } else {
          unsigned r = 0u;
#pragma unroll
          for (int kc = 0; kc < 13; ++kc) {
            uint4v u = __builtin_bit_cast(uint4v, ha[kc]);
            unsigned d = u.x | u.y | u.z | u.w;
            if (kc == 12) d = (lg < 2) ? d : 0u;
            r |= d;
          }
          ok = ((r & 0x80008000u) == 0u);
        }
        if (__all((int)ok)) break;
      }
      if (expm) {
#pragma unroll
        for (int kc = 0; kc < 13; ++kc) {
          uint4v u = __builtin_bit_cast(uint4v, ha[kc]);
          u.x &= 0x7FFF7FFFu; u.y &= 0x7FFF7FFFu;
          u.z &= 0x7FFF7FFFu; u.w &= 0x7FFF7FFFu;
          ha[kc] = __builtin_bit_cast(short8, u);
        }
      }
      if (lg >= 2) {
        short8 z;
#pragma unroll
        for (int q = 0; q < 8; ++q) z[q] = 0;
        ha[12] = z;
      }

      // ---- report consumption (data secured in regs) ----
      if (l == 0)
        st_u32(&prog[g * 64 + p], (unsigned)(t + 1));

      // ---- fc tile p + out row ----
      f32x4 hy = {0.f, 0.f, 0.f, 0.f};
#pragma unroll
      for (int kc = 0; kc < 13; ++kc)
        hy = __builtin_amdgcn_mfma_f32_16x16x32_bf16(ha[kc], whv[kc], hy, 0, 0, 0);
#pragma unroll
      for (int v = 0; v < 4; ++v) {
        float val = fmaxf(hy[v] + bfcv, 0.f) * woutv;
        val += __shfl_xor(val, 1);
        val += __shfl_xor(val, 2);
        val += __shfl_xor(val, 4);
        val += __shfl_xor(val, 8);
        if (ln == 0)
          yPart[(size_t)p * Tn * Bn + (size_t)t * Bn + b0 + (lg << 2) + v] = val;
      }
    }
  }
}

// ---------------- finalize: out = sigmoid(sum of 13 partials + b_out) ----------------
__global__ void finalize_kernel(const float* __restrict__ yPart,
                                const float* __restrict__ b_out,
                                float* __restrict__ out)
{
  int i = blockIdx.x * blockDim.x + threadIdx.x;
  if (i < Tn * Bn) {
    float sum = b_out[0];
#pragma unroll
    for (int p = 0; p < 13; ++p)
      sum += yPart[(size_t)p * Tn * Bn + i];
    out[i] = sigm(sum);
  }
}

extern "C" void kernel_launch(void* const* d_in, const int* in_sizes, int n_in,
                              void* d_out, int out_size, void* d_ws, size_t ws_size,
                              hipStream_t stream)
{
  const float* word  = (const float*)d_in[0];
  const float* W_ih  = (const float*)d_in[1];
  const float* W_hh  = (const float*)d_in[2];
  const float* b_ih  = (const float*)d_in[3];
  const float* b_hh  = (const float*)d_in[4];
  const float* W_fc  = (const float*)d_in[5];
  const float* b_fc  = (const float*)d_in[6];
  const float* W_out = (const float*)d_in[7];
  const float* b_out = (const float*)d_in[8];
  unsigned char* ws  = (unsigned char*)d_ws;

  const long long prep_items = 716800LL + 86528 + 1600 + 208 + 208 + 212992 + 256;
  prep_kernel<<<(int)((prep_items + 255) / 256), 256, 0, stream>>>(
      W_ih, W_hh, b_ih, b_hh, W_fc, b_fc, W_out, ws);
  lstm_persist<<<NSL + NHB, 256, 0, stream>>>(word, ws);
  finalize_kernel<<<(Tn * Bn + 255) / 256, 256, 0, stream>>>(
      (const float*)(ws + OFF_YPART), b_out, (float*)d_out);
}

// Round 13
// 4725.925 us; speedup vs baseline: 1.0360x; 1.0360x over previous
//
#include <hip/hip_runtime.h>

// ---------------- problem constants ----------------
#define Tn   2048
#define Bn   64
#define INn  27
#define H1n  400
#define KP   416          // padded fc K — Wfc row stride
#define NSL  50           // producer blocks (slices), 8 units each
#define NHB  13           // head blocks (fc tiles of 16 rows)
#define RING 8            // h ring depth; epoch parity = (t>>3)&1
// hbuf: [slot][g][s:52][r:16][u:8] bf16; 256 B per (g,s), wave-exclusive
#define HB_G    13312u    // 52 slice blocks (50 real + 2 pad) * 256 B
#define HB_SLOT 53248u    // 4 groups * HB_G

using short8 = __attribute__((ext_vector_type(8))) short;   // 8 bf16
using f32x4  = __attribute__((ext_vector_type(4))) float;   // MFMA acc
using uint4v = __attribute__((ext_vector_type(4))) unsigned;

// ---------------- workspace layout (bytes) ----------------
#define OFF_WBIG  0u         // bf16 [1600][448]  [Whh|pad|Wih]       1,433,600
#define OFF_WFC   1433600u   // bf16 [208][416]                         173,056
#define OFF_BSUM  1606656u   // f32  [1600]                               6,400
#define OFF_BFC   1613056u   // f32  [208]                                  832
#define OFF_WOUT  1613888u   // f32  [208]                                  832
#define OFF_HBUF  1614720u   // bf16 ring [8][4][52][16][8]             425,984
#define OFF_PROG  2040704u   // u32  [4][64] head progress                1,024
#define OFF_YPART 2041728u   // f32  [13][2048*64] head partials      6,815,744
// total 8,857,472

__device__ __forceinline__ unsigned short f2bf(float f) {
  unsigned u = __builtin_bit_cast(unsigned, f);
  u += 0x7fffu + ((u >> 16) & 1u);          // round-to-nearest-even
  return (unsigned short)(u >> 16);
}
__device__ __forceinline__ float sigm(float x) {
  float e = __builtin_amdgcn_exp2f(-1.44269504f * x);
  return __builtin_amdgcn_rcpf(1.0f + e);
}
__device__ __forceinline__ float tanh_(float x) {
  float e = __builtin_amdgcn_exp2f(2.88539008f * x);
  return 1.0f - 2.0f * __builtin_amdgcn_rcpf(e + 1.0f);
}

// ---- agent-coherent reads (sc0 sc1: L1/L2 bypass, L3 coherence point) ----
__device__ __forceinline__ unsigned ld_u32_wait(const unsigned* p) {
  unsigned v;
  asm volatile("global_load_dword %0, %1, off sc0 sc1\n\ts_waitcnt vmcnt(0)"
               : "=v"(v) : "v"(p) : "memory");
  return v;
}
__device__ __forceinline__ unsigned ld_u32_nw(const unsigned* p) {
  unsigned v;
  asm volatile("global_load_dword %0, %1, off sc0 sc1" : "=v"(v) : "v"(p) : "memory");
  return v;
}
__device__ __forceinline__ short8 ld_h16(const void* p) {
  short8 v;
  asm volatile("global_load_dwordx4 %0, %1, off sc0 sc1" : "=v"(v) : "v"(p) : "memory");
  return v;
}
// ---- publishes as atomic swaps: execute AT the L3 coherence point and
// leave the line allocated there (sc0sc1 stores write through to HBM — the
// 481 MB FETCH_SIZE signature). Fire-and-forget (no return: no sc0). ----
__device__ __forceinline__ void st_h8_at(void* p, unsigned long long v) {
  asm volatile("global_atomic_swap_x2 %0, %1, off" :: "v"(p), "v"(v) : "memory");
}
__device__ __forceinline__ void st_u32_at(void* p, unsigned v) {
  asm volatile("global_atomic_swap %0, %1, off" :: "v"(p), "v"(v) : "memory");
}

// MFMA with B operand pinned in AGPRs (weights resident; proven R5/R8/R9).
__device__ __forceinline__ f32x4 mfma_aw(short8 a, short8 w_agpr, f32x4 acc) {
  asm("v_mfma_f32_16x16x32_bf16 %0, %1, %2, %0"
      : "+v"(acc) : "v"(a), "a"(w_agpr));
  return acc;
}

// rowp (0..1599) -> original gate row. Slice s owns units 8s..8s+7 as
// 2 tiles: tile0 = gates i|f, tile1 = g|o (i/f split at col bit 3).
__device__ __forceinline__ int gate_row(int rowp) {
  int s    = rowp >> 5;
  int r32  = rowp & 31;
  int tile = r32 >> 4;
  int c    = r32 & 15;
  int gate = tile * 2 + (c >> 3);
  int u    = s * 8 + (c & 7);
  return gate * H1n + u;
}

// ---------------- prep ----------------
__global__ void prep_kernel(const float* __restrict__ Wih, const float* __restrict__ Whh,
                            const float* __restrict__ bih, const float* __restrict__ bhh,
                            const float* __restrict__ Wfc, const float* __restrict__ bfc,
                            const float* __restrict__ Wout,
                            unsigned char* __restrict__ ws)
{
  size_t i = (size_t)blockIdx.x * blockDim.x + threadIdx.x;
  const size_t n1 = (size_t)1600 * 448;   // Wbig       716800
  const size_t n2 = (size_t)208 * KP;     // Wfc          86528
  const size_t n3 = 1600;                 // bsum
  const size_t n4 = 208;                  // bfc
  const size_t n5 = 208;                  // wout
  const size_t n6 = (size_t)RING * HB_SLOT / 2;  // hbuf shorts 212992
  const size_t n7 = 256;                  // progress words

  if (i < n1) {
    unsigned short* p = (unsigned short*)(ws + OFF_WBIG);
    int rowp = (int)(i / 448), k = (int)(i % 448);
    int r = gate_row(rowp);
    float v = 0.0f;
    if (k < H1n)            v = Whh[(size_t)r * H1n + k];
    else if (k >= 416) { int jj = k - 416; if (jj < INn) v = Wih[(size_t)r * INn + jj]; }
    p[i] = f2bf(v);
    return;
  }
  i -= n1;
  if (i < n2) {
    unsigned short* p = (unsigned short*)(ws + OFF_WFC);
    int r = (int)(i / KP), k = (int)(i % KP);
    p[i] = (r < 200 && k < H1n) ? f2bf(Wfc[(size_t)r * H1n + k]) : (unsigned short)0;
    return;
  }
  i -= n2;
  if (i < n3) { int r = gate_row((int)i);
    ((float*)(ws + OFF_BSUM))[i] = bih[r] + bhh[r]; return; }
  i -= n3;
  if (i < n4) { ((float*)(ws + OFF_BFC))[i] = (i < 200) ? bfc[i] : 0.0f; return; }
  i -= n4;
  if (i < n5) { ((float*)(ws + OFF_WOUT))[i] = (i < 200) ? Wout[i] : 0.0f; return; }
  i -= n5;
  // hbuf init: 0x8000 (= parity 1) so epoch-0 (parity 0) checks can't
  // false-positive on unwritten data.
  if (i < n6) { ((unsigned short*)(ws + OFF_HBUF))[i] = 0x8000u; return; }
  i -= n6;
  if (i < n7) { ((unsigned*)(ws + OFF_PROG))[i] = 0u; return; }
}

// ---------------- persistent LSTM ----------------
// EXACT R9 structure (passed correctness + determinism tripwire; 4.65 ms).
// Single change: publishes (h, head progress) are global_atomic_swap so the
// data lands allocated in L3 instead of writing through to HBM. 63 blocks x
// 256 thr (wave = batch group). Blocks 0..49: producers (8 units, 2 gate
// tiles, AGPR weights). Blocks 50..62: heads (fc tile p). SYNC: parity-in-
// sign-bit (h_r >= 0); consumers accept only a fully parity-verified
// 13-chunk read. Heads report consumed-step in prog[]; producers gate
// publish on head progress >= t-7 (ring-overwrite safety).
__global__ void __launch_bounds__(256, 1)
lstm_persist(const float* __restrict__ word, unsigned char* __restrict__ ws)
{
  const int l  = threadIdx.x & 63;
  const int g  = threadIdx.x >> 6;   // batch group 0..3
  const int lg = l >> 4, ln = l & 15;
  const int b0 = g * 16;

  const unsigned short* Wbig = (const unsigned short*)(ws + OFF_WBIG);
  const unsigned short* Wfc2 = (const unsigned short*)(ws + OFF_WFC);
  const float* bsum  = (const float*)(ws + OFF_BSUM);
  const float* bfc2  = (const float*)(ws + OFF_BFC);
  const float* wout2 = (const float*)(ws + OFF_WOUT);
  char* hbase = (char*)(ws + OFF_HBUF);
  unsigned* prog = (unsigned*)(ws + OFF_PROG);
  float* yPart = (float*)(ws + OFF_YPART);

  // consumer fragment address: chunk kc covers slices kc*4+lg
  const size_t hoff = (size_t)g * HB_G + (size_t)lg * 256 + (size_t)ln * 16;

  __shared__ __align__(16) unsigned short smt2[4][16][8];   // [g][row][unit]

  if (blockIdx.x < NSL) {
    // ================= producer path =================
    const int s = blockIdx.x;

    short8 wv0[13], wv1[13], wx0, wx1;
#pragma unroll
    for (int kc = 0; kc < 13; ++kc) {
      wv0[kc] = *(const short8*)(Wbig + (size_t)(s * 32 + ln)      * 448 + kc * 32 + lg * 8);
      wv1[kc] = *(const short8*)(Wbig + (size_t)(s * 32 + 16 + ln) * 448 + kc * 32 + lg * 8);
    }
    wx0 = *(const short8*)(Wbig + (size_t)(s * 32 + ln)      * 448 + 13 * 32 + lg * 8);
    wx1 = *(const short8*)(Wbig + (size_t)(s * 32 + 16 + ln) * 448 + 13 * 32 + lg * 8);
    const float bs0 = bsum[s * 32 + ln];
    const float bs1 = bsum[s * 32 + 16 + ln];

    float c[4] = {0.f, 0.f, 0.f, 0.f};
    short8 ha[13];

    short8 xa;
    {
      const float* xrow = word + ((size_t)0 * Bn + b0 + ln) * INn;
#pragma unroll
      for (int q = 0; q < 8; ++q) {
        const int k = lg * 8 + q;
        xa[q] = (short)f2bf((k < INn) ? xrow[k] : 0.0f);
      }
    }

    for (int t = 0; t < Tn; ++t) {
      // ---- head-progress early load (monotonic -> stale-safe) ----
      unsigned hp = 0xFFFFFFFFu;
      if (l < NHB) hp = ld_u32_nw(&prog[g * 64 + l]);

      // ---- poll h(t-1) by parity: full verified read is the flag ----
      if (t > 0) {
        const char* hsrc = hbase + (size_t)((t + RING - 1) & (RING - 1)) * HB_SLOT + hoff;
        const bool expm = (((t - 1) >> 3) & 1) != 0;
        while (true) {
#pragma unroll
          for (int kc = 0; kc < 13; ++kc)
            ha[kc] = ld_h16(hsrc + kc * 1024);
          asm volatile("s_waitcnt vmcnt(0)" ::: "memory");
          __builtin_amdgcn_sched_barrier(0);
          bool ok;
          if (expm) {
            unsigned r = 0xFFFFFFFFu;
#pragma unroll
            for (int kc = 0; kc < 13; ++kc) {
              uint4v u = __builtin_bit_cast(uint4v, ha[kc]);
              unsigned d = u.x & u.y & u.z & u.w;
              if (kc == 12) d = (lg < 2) ? d : 0xFFFFFFFFu;   // mask pad slices
              r &= d;
            }
            ok = ((r & 0x80008000u) == 0x80008000u);
          } else {
            unsigned r = 0u;
#pragma unroll
            for (int kc = 0; kc < 13; ++kc) {
              uint4v u = __builtin_bit_cast(uint4v, ha[kc]);
              unsigned d = u.x | u.y | u.z | u.w;
              if (kc == 12) d = (lg < 2) ? d : 0u;             // mask pad slices
              r |= d;
            }
            ok = ((r & 0x80008000u) == 0u);
          }
          if (__all((int)ok)) break;
        }
        if (expm) {
#pragma unroll
          for (int kc = 0; kc < 13; ++kc) {
            uint4v u = __builtin_bit_cast(uint4v, ha[kc]);
            u.x &= 0x7FFF7FFFu; u.y &= 0x7FFF7FFFu;
            u.z &= 0x7FFF7FFFu; u.w &= 0x7FFF7FFFu;
            ha[kc] = __builtin_bit_cast(short8, u);
          }
        }
        if (lg >= 2) {          // pad-slice garbage: zero (NaN x 0 = NaN!)
          short8 z;
#pragma unroll
          for (int q = 0; q < 8; ++q) z[q] = 0;
          ha[12] = z;
        }
      }

      // ---- gates: 2 tiles x (13 h + 1 x) MFMA, weights from AGPRs ----
      f32x4 a0 = {bs0, bs0, bs0, bs0};
      f32x4 a1 = {bs1, bs1, bs1, bs1};
      if (t > 0) {
#pragma unroll
        for (int kc = 0; kc < 13; ++kc) {
          a0 = mfma_aw(ha[kc], wv0[kc], a0);
          a1 = mfma_aw(ha[kc], wv1[kc], a1);
        }
      }
      a0 = mfma_aw(xa, wx0, a0);
      a1 = mfma_aw(xa, wx1, a1);

      // ---- cell update; lanes l and l^8 share unit, hold i/f and g/o ----
      const bool hiHalf = (l & 8) != 0;
      float hr[4];
#pragma unroll
      for (int v = 0; v < 4; ++v) {
        float o0 = a0[v], o1 = a1[v];
        float p0 = __shfl_xor(o0, 8);
        float p1 = __shfl_xor(o1, 8);
        float iv = hiHalf ? p0 : o0;
        float fv = hiHalf ? o0 : p0;
        float gv = hiHalf ? p1 : o1;
        float ov = hiHalf ? o1 : p1;
        iv = sigm(iv); fv = sigm(fv); gv = tanh_(gv); ov = sigm(ov);
        float cn = fv * c[v] + iv * gv;
        float hn = ov * tanh_(cn);
        c[v]  = fmaxf(cn, 0.f);
        hr[v] = fmaxf(hn, 0.f);
      }
      // ---- wave-local transpose; embed parity of CURRENT step t ----
      const unsigned short pb = (unsigned short)(((t >> 3) & 1) << 15);
      if (!hiHalf) {
#pragma unroll
        for (int v = 0; v < 4; ++v)
          smt2[g][lg * 4 + v][ln] = (unsigned short)(f2bf(hr[v]) | pb);
      }
      asm volatile("s_waitcnt lgkmcnt(0)" ::: "memory");

      // ---- ring-overwrite gate: heads must have consumed step t-7 ----
      if (t >= RING) {
        const unsigned need = (unsigned)(t - (RING - 1));
        bool hok = (l < NHB) ? (hp >= need) : true;
        while (!__all((int)hok)) {
          if (l < NHB) hp = ld_u32_wait(&prog[g * 64 + l]);
          hok = (l < NHB) ? (hp >= need) : true;
        }
      }

      // ---- publish h(t): exclusive 256-B block via L3-allocating atomics ----
      {
        char* hdst = hbase + (size_t)(t & (RING - 1)) * HB_SLOT
                   + (size_t)g * HB_G + (size_t)s * 256;
        if (l < 32) {
          unsigned long long hv = ((const unsigned long long*)&smt2[g][0][0])[l];
          st_h8_at(hdst + l * 8, hv);
        }
      }

      // ---- x(t+1) prefetch ----
      if (t + 1 < Tn) {
        const float* xrow = word + ((size_t)(t + 1) * Bn + b0 + ln) * INn;
#pragma unroll
        for (int q = 0; q < 8; ++q) {
          const int k = lg * 8 + q;
          xa[q] = (short)f2bf((k < INn) ? xrow[k] : 0.0f);
        }
      }
    }
  } else {
    // ================= head-consumer path =================
    const int p = blockIdx.x - NSL;      // fc tile 0..12

    short8 whv[13];
    {
      const int r = p * 16 + ln;
#pragma unroll
      for (int kc = 0; kc < 13; ++kc)
        whv[kc] = *(const short8*)(Wfc2 + (size_t)r * KP + kc * 32 + lg * 8);
    }
    const float bfcv  = bfc2[p * 16 + ln];
    const float woutv = wout2[p * 16 + ln];
    short8 ha[13];

    for (int t = 0; t < Tn; ++t) {
      // ---- poll h(t) by parity ----
      const char* hsrc = hbase + (size_t)(t & (RING - 1)) * HB_SLOT + hoff;
      const bool expm = (((t >> 3) & 1) != 0);
      while (true) {
#pragma unroll
        for (int kc = 0; kc < 13; ++kc)
          ha[kc] = ld_h16(hsrc + kc * 1024);
        asm volatile("s_waitcnt vmcnt(0)" ::: "memory");
        __builtin_amdgcn_sched_barrier(0);
        bool ok;
        if (expm) {
          unsigned r = 0xFFFFFFFFu;
#pragma unroll
          for (int kc = 0; kc < 13; ++kc) {
            uint4v u = __builtin_bit_cast(uint4v, ha[kc]);
            unsigned d = u.x & u.y & u.z & u.w;
            if (kc == 12) d = (lg < 2) ? d : 0xFFFFFFFFu;
            r &= d;
          }
          ok = ((r & 0x80008000u) == 0x80008000u);
        } else {
          unsigned r = 0u;
#pragma unroll
          for (int kc = 0; kc < 13; ++kc) {
            uint4v u = __builtin_bit_cast(uint4v, ha[kc]);
            unsigned d = u.x | u.y | u.z | u.w;
            if (kc == 12) d = (lg < 2) ? d : 0u;
            r |= d;
          }
          ok = ((r & 0x80008000u) == 0u);
        }
        if (__all((int)ok)) break;
      }
      if (expm) {
#pragma unroll
        for (int kc = 0; kc < 13; ++kc) {
          uint4v u = __builtin_bit_cast(uint4v, ha[kc]);
          u.x &= 0x7FFF7FFFu; u.y &= 0x7FFF7FFFu;
          u.z &= 0x7FFF7FFFu; u.w &= 0x7FFF7FFFu;
          ha[kc] = __builtin_bit_cast(short8, u);
        }
      }
      if (lg >= 2) {
        short8 z;
#pragma unroll
        for (int q = 0; q < 8; ++q) z[q] = 0;
        ha[12] = z;
      }

      // ---- report consumption via atomic (L3-allocating) ----
      if (l == 0)
        st_u32_at(&prog[g * 64 + p], (unsigned)(t + 1));

      // ---- fc tile p + out row ----
      f32x4 hy = {0.f, 0.f, 0.f, 0.f};
#pragma unroll
      for (int kc = 0; kc < 13; ++kc)
        hy = __builtin_amdgcn_mfma_f32_16x16x32_bf16(ha[kc], whv[kc], hy, 0, 0, 0);
#pragma unroll
      for (int v = 0; v < 4; ++v) {
        float val = fmaxf(hy[v] + bfcv, 0.f) * woutv;
        val += __shfl_xor(val, 1);
        val += __shfl_xor(val, 2);
        val += __shfl_xor(val, 4);
        val += __shfl_xor(val, 8);
        if (ln == 0)
          yPart[(size_t)p * Tn * Bn + (size_t)t * Bn + b0 + (lg << 2) + v] = val;
      }
    }
  }
}

// ---------------- finalize: out = sigmoid(sum of 13 partials + b_out) ----------------
__global__ void finalize_kernel(const float* __restrict__ yPart,
                                const float* __restrict__ b_out,
                                float* __restrict__ out)
{
  int i = blockIdx.x * blockDim.x + threadIdx.x;
  if (i < Tn * Bn) {
    float sum = b_out[0];
#pragma unroll
    for (int p = 0; p < 13; ++p)
      sum += yPart[(size_t)p * Tn * Bn + i];
    out[i] = sigm(sum);
  }
}

extern "C" void kernel_launch(void* const* d_in, const int* in_sizes, int n_in,
                              void* d_out, int out_size, void* d_ws, size_t ws_size,
                              hipStream_t stream)
{
  const float* word  = (const float*)d_in[0];
  const float* W_ih  = (const float*)d_in[1];
  const float* W_hh  = (const float*)d_in[2];
  const float* b_ih  = (const float*)d_in[3];
  const float* b_hh  = (const float*)d_in[4];
  const float* W_fc  = (const float*)d_in[5];
  const float* b_fc  = (const float*)d_in[6];
  const float* W_out = (const float*)d_in[7];
  const float* b_out = (const float*)d_in[8];
  unsigned char* ws  = (unsigned char*)d_ws;

  const long long prep_items = 716800LL + 86528 + 1600 + 208 + 208 + 212992 + 256;
  prep_kernel<<<(int)((prep_items + 255) / 256), 256, 0, stream>>>(
      W_ih, W_hh, b_ih, b_hh, W_fc, b_fc, W_out, ws);
  lstm_persist<<<NSL + NHB, 256, 0, stream>>>(word, ws);
  finalize_kernel<<<(Tn * Bn + 255) / 256, 256, 0, stream>>>(
      (const float*)(ws + OFF_YPART), b_out, (float*)d_out);
}